// Round 14
// baseline (105.898 us; speedup 1.0000x reference)
//
#include <hip/hip_runtime.h>

// Quantized 3x3 conv, stride 1, pad 1 (MI355X / gfx950):
//   x: [32,64,112,112] fp32 -> uint4-range [0,15]
//   w: [128,64,3,3]    fp32 -> int4-range  [-8,7]
//   out: [32,128,112,112] fp32 (integer-exact)
//
// R14 = R9 + 2-pair software pipeline (phase de-serialization):
//   block = 4 output rows as two sequential row-pairs with DISJOINT 4-row
//   LDS slabs (58.4 KB total -> still 2 blocks/CU; VGPR ~= R9 since staging
//   is zero-register global_load_lds).
//     DMA slab0 -> barrier -> K0 -> issue DMA slab1 (AFTER K0's last weight
//     load: in-order vmcnt retirement means an early DMA would poison every
//     weight wait -- R11's bug) -> pair0 stores -> barrier -> K1 -> stores.
//   Pair-0's HBM store drain overlaps pair-1's K-loop; slab1 DMA latency
//   hides under the pair-0 epilogue.
//
// k_prep: blocks 0..287: quantize weights -> fragment-major
//           wq[ks][coTile(8)][lane(64)][16B]  (exact MFMA B-fragment order)
//         blocks 288+ : quantize+transpose x -> xq[n][hp][wp][c] int8
//           (padded 114x114, zero border).
// k_conv: 512 thr / 8 waves; wave = 1 row (7x16 sp) x 32 co per pair;
//         weights from global L2, prefetch depth 2; 14 MFMA
//         v_mfma_i32_16x16x64_i8 per ks per wave per pair.

#define CIN  64
#define HH   112
#define WW   112
#define HW   (HH * WW)
#define COUT 128
#define HP   114
#define WP   114
#define KTOT 576

#define XQ_BYTES (32 * HP * WP * 64)     // 26,615,808
#define NWBLK 288                        // 288*256 = 73728 weight bytes
#define NXBLK (32 * 57)                  // activation prep blocks (2 rows each)
#define NCONV 896                        // 32 img * 28 quad-row strips = 8*112

#define ROWB (WP * 64)                   // 7296 B per padded row
#define SLAB_BYTES (4 * ROWB)            // 29,184 B (4 padded rows)

typedef __attribute__((ext_vector_type(4))) int int32x4;

__device__ __forceinline__ void gld_lds16(const char* g, char* l) {
    __builtin_amdgcn_global_load_lds(
        (const __attribute__((address_space(1))) void*)g,
        (__attribute__((address_space(3))) void*)l, 16, 0, 0);
}

__global__ __launch_bounds__(256) void k_prep(const float* __restrict__ x,
                                              const float* __restrict__ w,
                                              char* __restrict__ xq,
                                              char* __restrict__ wq) {
    const int bid = blockIdx.x, tid = threadIdx.x;
    if (bid < NWBLK) {
        // ---- weights, fragment-major: idx = dest byte ----
        // idx = ks*8192 + ct*1024 + ln*16 + j
        // -> cout = ct*16 + (ln&15), c = (ln>>4)*16 + j, kh = ks/3, kw = ks%3
        int idx = bid * 256 + tid;
        int ks  = idx / 8192;
        int r2  = idx % 8192;
        int ct  = r2 / 1024;
        int r3  = r2 % 1024;
        int ln  = r3 / 16;
        int j   = r3 % 16;
        int o   = ct * 16 + (ln & 15);
        int c   = (ln >> 4) * 16 + j;
        int kh  = ks / 3, kw = ks % 3;
        float q = fminf(fmaxf(rintf(w[((o * CIN + c) * 3 + kh) * 3 + kw]), -8.0f), 7.0f);
        wq[idx] = (char)(int)q;
        return;
    }
    // ---- activations: xq[n][hp][wp][c], zero border ----
    const int rid = bid - NWBLK;          // 0..1823
    const int n  = rid / 57;
    const int hp = (rid % 57) * 2 + (tid >> 7);
    const int wp = tid & 127;
    if (wp >= WP) return;
    char* dst = xq + (((size_t)n * HP + hp) * WP + wp) * 64;
    int32x4* d4 = (int32x4*)dst;
    if (hp == 0 || hp == HP - 1 || wp == 0 || wp == WP - 1) {
#pragma unroll
        for (int i = 0; i < 4; ++i) d4[i] = (int32x4)(0);
        return;
    }
    const int h = hp - 1, ww = wp - 1;
    const float* px = x + (((size_t)n * CIN) * HH + h) * WW + ww;
    unsigned int buf[16];
#pragma unroll
    for (int cw = 0; cw < 16; ++cw) {
        unsigned int word = 0;
#pragma unroll
        for (int j = 0; j < 4; ++j) {
            float v = px[(size_t)(cw * 4 + j) * HW];
            float q = fminf(fmaxf(rintf(v), 0.0f), 15.0f);
            word |= ((unsigned int)(int)q) << (8 * j);
        }
        buf[cw] = word;
    }
#pragma unroll
    for (int i = 0; i < 4; ++i) {
        int32x4 v;
        v.x = (int)buf[i * 4 + 0];
        v.y = (int)buf[i * 4 + 1];
        v.z = (int)buf[i * 4 + 2];
        v.w = (int)buf[i * 4 + 3];
        d4[i] = v;
    }
}

__global__ __launch_bounds__(512, 4) void k_conv(const char* __restrict__ xq,
                                                 const char* __restrict__ wq,
                                                 float* __restrict__ out) {
    __shared__ char slab[2 * SLAB_BYTES];   // 58,368 B: two disjoint 4-row slabs

    const int tid = threadIdx.x;
    // XCD chunking (896 = 8*112, bijective): consecutive nids = consecutive
    // 4-row strips of the same image -> halo-row L2 reuse within an XCD.
    const int nid = (blockIdx.x & 7) * (NCONV / 8) + (blockIdx.x >> 3);
    const int n   = nid / 28;
    const int h0  = (nid % 28) * 4;       // output rows h0..h0+3

    const int wave = tid >> 6;            // 0..7
    const int lane = tid & 63;

    // padded rows for pair0: h0..h0+3; pair1: h0+2..h0+5 (contiguous in xq)
    const char* src0 = xq + (size_t)n * (HP * ROWB) + (size_t)h0 * ROWB;

    // ---- DMA slab0 (zero-VGPR): wave-uniform LDS base + lane*16 ----
#pragma unroll
    for (int k = 0; k < 4; ++k) {
        const int ch  = wave + k * 8;                 // 1KB chunk index
        const int off = ch * 1024 + lane * 16;
        if (off < SLAB_BYTES)
            gld_lds16(src0 + off, slab + ch * 1024);
    }
    __syncthreads();   // drains slab0 DMA (vmcnt 0) + barrier

    const int l15 = lane & 15;
    const int lk  = lane >> 4;            // 16-byte k-chunk within 64 channels
    const int rw  = wave >> 2;            // output row within pair (0..1)
    const int Q   = wave & 3;             // cout quarter (32 couts)

    // B (weights, fragment-major): frag(ks, ct=Q*2+tO) at (ks*8+ct)*1024 + lane*16
    const char* wbase = wq + (Q * 2) * 1024 + lane * 16;

    int32x4 acc[7][2];
    int32x4 b0[2], b1[2], b2[2];

    // ================= pair 0: output rows h0+rw, slab0 =================
#pragma unroll
    for (int i = 0; i < 7; ++i) { acc[i][0] = (int32x4)(0); acc[i][1] = (int32x4)(0); }
    b0[0] = *(const int32x4*)(wbase);
    b0[1] = *(const int32x4*)(wbase + 1024);
    b1[0] = *(const int32x4*)(wbase + 8192);
    b1[1] = *(const int32x4*)(wbase + 8192 + 1024);
#pragma unroll
    for (int ks = 0; ks < 9; ++ks) {
        const int ksn = (ks + 2 <= 8) ? ks + 2 : 8;
        b2[0] = *(const int32x4*)(wbase + ksn * 8192);
        b2[1] = *(const int32x4*)(wbase + ksn * 8192 + 1024);
        const int kh = ks / 3, kw = ks % 3;
        const char* arow = &slab[(((rw + kh) * WP) + l15 + kw) * 64 + lk * 16];
        int32x4 af[7];
#pragma unroll
        for (int wt = 0; wt < 7; ++wt)
            af[wt] = *(const int32x4*)(arow + wt * 1024);
#pragma unroll
        for (int tO = 0; tO < 2; ++tO)
#pragma unroll
            for (int wt = 0; wt < 7; ++wt)
                acc[wt][tO] = __builtin_amdgcn_mfma_i32_16x16x64_i8(af[wt], b0[tO], acc[wt][tO], 0, 0, 0);
        b0[0] = b1[0]; b0[1] = b1[1];
        b1[0] = b2[0]; b1[1] = b2[1];
    }

    // ---- issue slab1 DMA now: AFTER all pair-0 weight loads (clean vmcnt),
    //      BEFORE pair-0 stores (latency hides under the epilogue) ----
#pragma unroll
    for (int k = 0; k < 4; ++k) {
        const int ch  = wave + k * 8;
        const int off = ch * 1024 + lane * 16;
        if (off < SLAB_BYTES)
            gld_lds16(src0 + 2 * ROWB + off, slab + SLAB_BYTES + ch * 1024);
    }

    // ---- pair-0 epilogue: D col(l15)=cout, row(lk*4+reg)=spatial w ----
    {
        const int hgl = h0 + rw;
#pragma unroll
        for (int wt = 0; wt < 7; ++wt)
#pragma unroll
            for (int tO = 0; tO < 2; ++tO) {
                const int co = Q * 32 + tO * 16 + l15;
                float4 v;
                v.x = (float)acc[wt][tO][0];
                v.y = (float)acc[wt][tO][1];
                v.z = (float)acc[wt][tO][2];
                v.w = (float)acc[wt][tO][3];
                *(float4*)(&out[(((size_t)n * COUT + co) * HH + hgl) * WW + wt * 16 + lk * 4]) = v;
            }
    }

    __syncthreads();   // slab1 DMA drained (mostly landed under epilogue)

    // ================= pair 1: output rows h0+2+rw, slab1 =================
#pragma unroll
    for (int i = 0; i < 7; ++i) { acc[i][0] = (int32x4)(0); acc[i][1] = (int32x4)(0); }
    b0[0] = *(const int32x4*)(wbase);
    b0[1] = *(const int32x4*)(wbase + 1024);
    b1[0] = *(const int32x4*)(wbase + 8192);
    b1[1] = *(const int32x4*)(wbase + 8192 + 1024);
#pragma unroll
    for (int ks = 0; ks < 9; ++ks) {
        const int ksn = (ks + 2 <= 8) ? ks + 2 : 8;
        b2[0] = *(const int32x4*)(wbase + ksn * 8192);
        b2[1] = *(const int32x4*)(wbase + ksn * 8192 + 1024);
        const int kh = ks / 3, kw = ks % 3;
        const char* arow = &slab[SLAB_BYTES + (((rw + kh) * WP) + l15 + kw) * 64 + lk * 16];
        int32x4 af[7];
#pragma unroll
        for (int wt = 0; wt < 7; ++wt)
            af[wt] = *(const int32x4*)(arow + wt * 1024);
#pragma unroll
        for (int tO = 0; tO < 2; ++tO)
#pragma unroll
            for (int wt = 0; wt < 7; ++wt)
                acc[wt][tO] = __builtin_amdgcn_mfma_i32_16x16x64_i8(af[wt], b0[tO], acc[wt][tO], 0, 0, 0);
        b0[0] = b1[0]; b0[1] = b1[1];
        b1[0] = b2[0]; b1[1] = b2[1];
    }
    {
        const int hgl = h0 + 2 + rw;
#pragma unroll
        for (int wt = 0; wt < 7; ++wt)
#pragma unroll
            for (int tO = 0; tO < 2; ++tO) {
                const int co = Q * 32 + tO * 16 + l15;
                float4 v;
                v.x = (float)acc[wt][tO][0];
                v.y = (float)acc[wt][tO][1];
                v.z = (float)acc[wt][tO][2];
                v.w = (float)acc[wt][tO][3];
                *(float4*)(&out[(((size_t)n * COUT + co) * HH + hgl) * WW + wt * 16 + lk * 4]) = v;
            }
    }
}

extern "C" void kernel_launch(void* const* d_in, const int* in_sizes, int n_in,
                              void* d_out, int out_size, void* d_ws, size_t ws_size,
                              hipStream_t stream) {
    const float* x = (const float*)d_in[0];
    const float* w = (const float*)d_in[1];
    float* out = (float*)d_out;

    char* xq = (char*)d_ws;
    char* wq = xq + XQ_BYTES;

    hipLaunchKernelGGL(k_prep, dim3(NWBLK + NXBLK), dim3(256), 0, stream, x, w, xq, wq);
    hipLaunchKernelGGL(k_conv, dim3(NCONV), dim3(512), 0, stream, xq, wq, out);
}

// Round 15
// 92.139 us; speedup vs baseline: 1.1493x; 1.1493x over previous
//
#include <hip/hip_runtime.h>

// Quantized 3x3 conv, stride 1, pad 1 (MI355X / gfx950):
//   x: [32,64,112,112] fp32 -> uint4-range [0,15]
//   w: [128,64,3,3]    fp32 -> int4-range  [-8,7]
//   out: [32,128,112,112] fp32 (integer-exact)
//
// R15 = R9 (best, 87.2 us) with FINER block granularity: block = 1 output
// row x 128 cout, 256 thr / 4 waves, 3-row LDS slab (21.9 KB) -> 4 resident
// blocks/CU (vs R9's 2) = 4 independent barrier domains per CU. One block's
// epilogue store burst overlaps the other blocks' stage/K-loop phases --
// de-phasing via scheduler instead of in-block pipelining (R10/R11/R14 all
// showed in-block pipelines self-serialize on vmcnt drains).
//
// k_prep: blocks 0..287: quantize weights -> fragment-major
//           wq[ks][coTile(8)][lane(64)][16B]  (exact MFMA B-fragment order)
//         blocks 288+ : quantize+transpose x -> xq[n][hp][wp][c] int8
//           (padded 114x114, zero border).
// k_conv: wave = 1 row (7x16 sp) x 32 cout; weights from global L2,
//         prefetch depth 2; 14 MFMA v_mfma_i32_16x16x64_i8 per ks per wave.

#define CIN  64
#define HH   112
#define WW   112
#define HW   (HH * WW)
#define COUT 128
#define HP   114
#define WP   114
#define KTOT 576

#define XQ_BYTES (32 * HP * WP * 64)     // 26,615,808
#define NWBLK 288                        // 288*256 = 73728 weight bytes
#define NXBLK (32 * 57)                  // activation prep blocks (2 rows each)
#define NCONV (32 * HH)                  // 3584 = 8 * 448 (bijective XCD chunking)

#define ROWB (WP * 64)                   // 7296 B per padded row
#define SLAB_BYTES (3 * ROWB)            // 21,888 B (3 padded rows)
#define SLAB_U16   (SLAB_BYTES / 16)     // 1368 16-byte units

typedef __attribute__((ext_vector_type(4))) int int32x4;

__global__ __launch_bounds__(256) void k_prep(const float* __restrict__ x,
                                              const float* __restrict__ w,
                                              char* __restrict__ xq,
                                              char* __restrict__ wq) {
    const int bid = blockIdx.x, tid = threadIdx.x;
    if (bid < NWBLK) {
        // ---- weights, fragment-major: idx = dest byte ----
        // idx = ks*8192 + ct*1024 + ln*16 + j
        // -> cout = ct*16 + (ln&15), c = (ln>>4)*16 + j, kh = ks/3, kw = ks%3
        int idx = bid * 256 + tid;
        int ks  = idx / 8192;
        int r2  = idx % 8192;
        int ct  = r2 / 1024;
        int r3  = r2 % 1024;
        int ln  = r3 / 16;
        int j   = r3 % 16;
        int o   = ct * 16 + (ln & 15);
        int c   = (ln >> 4) * 16 + j;
        int kh  = ks / 3, kw = ks % 3;
        float q = fminf(fmaxf(rintf(w[((o * CIN + c) * 3 + kh) * 3 + kw]), -8.0f), 7.0f);
        wq[idx] = (char)(int)q;
        return;
    }
    // ---- activations: xq[n][hp][wp][c], zero border ----
    const int rid = bid - NWBLK;          // 0..1823
    const int n  = rid / 57;
    const int hp = (rid % 57) * 2 + (tid >> 7);
    const int wp = tid & 127;
    if (wp >= WP) return;
    char* dst = xq + (((size_t)n * HP + hp) * WP + wp) * 64;
    int32x4* d4 = (int32x4*)dst;
    if (hp == 0 || hp == HP - 1 || wp == 0 || wp == WP - 1) {
#pragma unroll
        for (int i = 0; i < 4; ++i) d4[i] = (int32x4)(0);
        return;
    }
    const int h = hp - 1, ww = wp - 1;
    const float* px = x + (((size_t)n * CIN) * HH + h) * WW + ww;
    unsigned int buf[16];
#pragma unroll
    for (int cw = 0; cw < 16; ++cw) {
        unsigned int word = 0;
#pragma unroll
        for (int j = 0; j < 4; ++j) {
            float v = px[(size_t)(cw * 4 + j) * HW];
            float q = fminf(fmaxf(rintf(v), 0.0f), 15.0f);
            word |= ((unsigned int)(int)q) << (8 * j);
        }
        buf[cw] = word;
    }
#pragma unroll
    for (int i = 0; i < 4; ++i) {
        int32x4 v;
        v.x = (int)buf[i * 4 + 0];
        v.y = (int)buf[i * 4 + 1];
        v.z = (int)buf[i * 4 + 2];
        v.w = (int)buf[i * 4 + 3];
        d4[i] = v;
    }
}

__global__ __launch_bounds__(256, 4) void k_conv(const char* __restrict__ xq,
                                                 const char* __restrict__ wq,
                                                 float* __restrict__ out) {
    __shared__ char slab[SLAB_BYTES];     // 21,888 B: padded rows h..h+2

    const int tid = threadIdx.x;
    // XCD chunking (3584 = 8*448, bijective): consecutive nids = consecutive
    // rows of the same image -> halo-row L2/L3 reuse within an XCD.
    const int nid = (blockIdx.x & 7) * (NCONV / 8) + (blockIdx.x >> 3);
    const int n   = nid / HH;
    const int h   = nid % HH;             // output row

    // ---- stage: padded rows h..h+2 of xq are CONTIGUOUS -> linear memcpy ----
    const char* src = xq + (size_t)n * (HP * ROWB) + (size_t)h * ROWB;
#pragma unroll
    for (int k = 0; k < 6; ++k) {
        const int u = tid + k * 256;
        if (u < SLAB_U16)
            *(int32x4*)(&slab[u * 16]) = *(const int32x4*)(src + u * 16);
    }
    __syncthreads();

    const int wave = tid >> 6;            // 0..3 = cout quarter
    const int lane = tid & 63;
    const int l15  = lane & 15;
    const int lk   = lane >> 4;           // 16-byte k-chunk within 64 channels
    const int Q    = wave;                // cout quarter (32 couts)

    // B (weights, fragment-major): frag(ks, ct=Q*2+tO) at (ks*8+ct)*1024 + lane*16
    const char* wbase = wq + (Q * 2) * 1024 + lane * 16;

    int32x4 acc[7][2];
#pragma unroll
    for (int i = 0; i < 7; ++i) {
        acc[i][0] = (int32x4)(0);
        acc[i][1] = (int32x4)(0);
    }

    // Weight prefetch depth 2: b0 = frag(ks), b1 = frag(ks+1), issue ks+2.
    int32x4 b0[2], b1[2], b2[2];
    b0[0] = *(const int32x4*)(wbase);
    b0[1] = *(const int32x4*)(wbase + 1024);
    b1[0] = *(const int32x4*)(wbase + 8192);
    b1[1] = *(const int32x4*)(wbase + 8192 + 1024);

#pragma unroll
    for (int ks = 0; ks < 9; ++ks) {
        {
            const int ksn = (ks + 2 <= 8) ? ks + 2 : 8;   // clamp: stay in-bounds
            b2[0] = *(const int32x4*)(wbase + ksn * 8192);
            b2[1] = *(const int32x4*)(wbase + ksn * 8192 + 1024);
        }
        const int kh = ks / 3, kw = ks % 3;
        // A: slab row kh, padded col (wt*16 + l15 + kw), chunk lk
        const char* arow = &slab[((kh * WP) + l15 + kw) * 64 + lk * 16];
        int32x4 af[7];
#pragma unroll
        for (int wt = 0; wt < 7; ++wt)
            af[wt] = *(const int32x4*)(arow + wt * 1024);   // wt*16 cols * 64B
#pragma unroll
        for (int tO = 0; tO < 2; ++tO)
#pragma unroll
            for (int wt = 0; wt < 7; ++wt)
                acc[wt][tO] = __builtin_amdgcn_mfma_i32_16x16x64_i8(af[wt], b0[tO], acc[wt][tO], 0, 0, 0);
        b0[0] = b1[0]; b0[1] = b1[1];
        b1[0] = b2[0]; b1[1] = b2[1];
    }

    // ---- epilogue: D col(l15)=cout, row(lk*4+reg)=spatial w -> float4 ----
#pragma unroll
    for (int wt = 0; wt < 7; ++wt) {
#pragma unroll
        for (int tO = 0; tO < 2; ++tO) {
            const int co = Q * 32 + tO * 16 + l15;
            float4 v;
            v.x = (float)acc[wt][tO][0];
            v.y = (float)acc[wt][tO][1];
            v.z = (float)acc[wt][tO][2];
            v.w = (float)acc[wt][tO][3];
            *(float4*)(&out[(((size_t)n * COUT + co) * HH + h) * WW + wt * 16 + lk * 4]) = v;
        }
    }
}

extern "C" void kernel_launch(void* const* d_in, const int* in_sizes, int n_in,
                              void* d_out, int out_size, void* d_ws, size_t ws_size,
                              hipStream_t stream) {
    const float* x = (const float*)d_in[0];
    const float* w = (const float*)d_in[1];
    float* out = (float*)d_out;

    char* xq = (char*)d_ws;
    char* wq = xq + XQ_BYTES;

    hipLaunchKernelGGL(k_prep, dim3(NWBLK + NXBLK), dim3(256), 0, stream, x, w, xq, wq);
    hipLaunchKernelGGL(k_conv, dim3(NCONV), dim3(256), 0, stream, xq, wq, out);
}

// Round 16
// 87.137 us; speedup vs baseline: 1.2153x; 1.0574x over previous
//
#include <hip/hip_runtime.h>

// Quantized 3x3 conv, stride 1, pad 1 (MI355X / gfx950):
//   x: [32,64,112,112] fp32 -> uint4-range [0,15]
//   w: [128,64,3,3]    fp32 -> int4-range  [-8,7]
//   out: [32,128,112,112] fp32 (integer-exact)
//
// R16: wt-major STORE-STREAMING conv. All 18 weight B-fragments live in
// registers (72 VGPR, loaded once per block, L2 latency hidden under the
// slab stage). Loop order: for each of 7 output w-columns -> 9 LDS A-reads,
// 18 MFMA, cvt, 2 float4 stores IMMEDIATELY. Stores issue in 7 spread
// bursts across the K-phase (waves never block on store vmcnt), smoothing
// HBM write demand and shrinking the block-retire drain 7x -- the
// serialization that R10/R11/R14/R15 failed to fix with inter-block tricks.
// acc live range drops 56->8 VGPR (wreg +72, net ~150) -> 3 blocks/CU.
//
// k_prep: blocks 0..287: quantize weights -> fragment-major
//           wq[ks][coTile(8)][lane(64)][16B]  (exact MFMA B-fragment order)
//         blocks 288+ : quantize+transpose x -> xq[n][hp][wp][c] int8
//           (padded 114x114, zero border).
// k_conv: block = 1 output row x 128 cout, 256 thr / 4 waves, 3-row slab
//         (21.9 KB LDS). Wave = 1 row (7x16 sp) x 32 cout.

#define CIN  64
#define HH   112
#define WW   112
#define HW   (HH * WW)
#define COUT 128
#define HP   114
#define WP   114
#define KTOT 576

#define XQ_BYTES (32 * HP * WP * 64)     // 26,615,808
#define NWBLK 288                        // 288*256 = 73728 weight bytes
#define NXBLK (32 * 57)                  // activation prep blocks (2 rows each)
#define NCONV (32 * HH)                  // 3584 = 8 * 448 (bijective XCD chunking)

#define ROWB (WP * 64)                   // 7296 B per padded row
#define SLAB_BYTES (3 * ROWB)            // 21,888 B (3 padded rows)
#define SLAB_U16   (SLAB_BYTES / 16)     // 1368 16-byte units

typedef __attribute__((ext_vector_type(4))) int int32x4;

__global__ __launch_bounds__(256) void k_prep(const float* __restrict__ x,
                                              const float* __restrict__ w,
                                              char* __restrict__ xq,
                                              char* __restrict__ wq) {
    const int bid = blockIdx.x, tid = threadIdx.x;
    if (bid < NWBLK) {
        // ---- weights, fragment-major: idx = dest byte ----
        // idx = ks*8192 + ct*1024 + ln*16 + j
        // -> cout = ct*16 + (ln&15), c = (ln>>4)*16 + j, kh = ks/3, kw = ks%3
        int idx = bid * 256 + tid;
        int ks  = idx / 8192;
        int r2  = idx % 8192;
        int ct  = r2 / 1024;
        int r3  = r2 % 1024;
        int ln  = r3 / 16;
        int j   = r3 % 16;
        int o   = ct * 16 + (ln & 15);
        int c   = (ln >> 4) * 16 + j;
        int kh  = ks / 3, kw = ks % 3;
        float q = fminf(fmaxf(rintf(w[((o * CIN + c) * 3 + kh) * 3 + kw]), -8.0f), 7.0f);
        wq[idx] = (char)(int)q;
        return;
    }
    // ---- activations: xq[n][hp][wp][c], zero border ----
    const int rid = bid - NWBLK;          // 0..1823
    const int n  = rid / 57;
    const int hp = (rid % 57) * 2 + (tid >> 7);
    const int wp = tid & 127;
    if (wp >= WP) return;
    char* dst = xq + (((size_t)n * HP + hp) * WP + wp) * 64;
    int32x4* d4 = (int32x4*)dst;
    if (hp == 0 || hp == HP - 1 || wp == 0 || wp == WP - 1) {
#pragma unroll
        for (int i = 0; i < 4; ++i) d4[i] = (int32x4)(0);
        return;
    }
    const int h = hp - 1, ww = wp - 1;
    const float* px = x + (((size_t)n * CIN) * HH + h) * WW + ww;
    unsigned int buf[16];
#pragma unroll
    for (int cw = 0; cw < 16; ++cw) {
        unsigned int word = 0;
#pragma unroll
        for (int j = 0; j < 4; ++j) {
            float v = px[(size_t)(cw * 4 + j) * HW];
            float q = fminf(fmaxf(rintf(v), 0.0f), 15.0f);
            word |= ((unsigned int)(int)q) << (8 * j);
        }
        buf[cw] = word;
    }
#pragma unroll
    for (int i = 0; i < 4; ++i) {
        int32x4 v;
        v.x = (int)buf[i * 4 + 0];
        v.y = (int)buf[i * 4 + 1];
        v.z = (int)buf[i * 4 + 2];
        v.w = (int)buf[i * 4 + 3];
        d4[i] = v;
    }
}

__global__ __launch_bounds__(256, 3) void k_conv(const char* __restrict__ xq,
                                                 const char* __restrict__ wq,
                                                 float* __restrict__ out) {
    __shared__ char slab[SLAB_BYTES];     // 21,888 B: padded rows h..h+2

    const int tid = threadIdx.x;
    // XCD chunking (3584 = 8*448, bijective): consecutive nids = consecutive
    // rows of the same image -> halo-row L2/L3 reuse within an XCD.
    const int nid = (blockIdx.x & 7) * (NCONV / 8) + (blockIdx.x >> 3);
    const int n   = nid / HH;
    const int h   = nid % HH;             // output row

    const int wave = tid >> 6;            // 0..3 = cout quarter
    const int lane = tid & 63;
    const int l15  = lane & 15;
    const int lk   = lane >> 4;           // 16-byte k-chunk within 64 channels
    const int Q    = wave;                // cout quarter (32 couts)

    // ---- issue all 18 weight fragment loads first (L2 latency hides
    //      under the slab stage below) ----
    const char* wbase = wq + (Q * 2) * 1024 + lane * 16;
    int32x4 wreg[9][2];
#pragma unroll
    for (int ks = 0; ks < 9; ++ks) {
        wreg[ks][0] = *(const int32x4*)(wbase + ks * 8192);
        wreg[ks][1] = *(const int32x4*)(wbase + ks * 8192 + 1024);
    }

    // ---- stage: padded rows h..h+2 of xq are CONTIGUOUS -> linear memcpy ----
    const char* src = xq + (size_t)n * (HP * ROWB) + (size_t)h * ROWB;
#pragma unroll
    for (int k = 0; k < 6; ++k) {
        const int u = tid + k * 256;
        if (u < SLAB_U16)
            *(int32x4*)(&slab[u * 16]) = *(const int32x4*)(src + u * 16);
    }
    __syncthreads();

    float* obase = out + (((size_t)n * COUT + Q * 32 + l15) * HH + h) * WW + lk * 4;

    // ---- wt-major: compute one w-column's 2 tiles, store immediately ----
#pragma unroll
    for (int wt = 0; wt < 7; ++wt) {
        int32x4 af[9];
#pragma unroll
        for (int ks = 0; ks < 9; ++ks) {
            const int kh = ks / 3, kw = ks % 3;
            af[ks] = *(const int32x4*)(&slab[((kh * WP) + wt * 16 + l15 + kw) * 64 + lk * 16]);
        }
        int32x4 a0 = (int32x4)(0);
        int32x4 a1 = (int32x4)(0);
#pragma unroll
        for (int ks = 0; ks < 9; ++ks) {
            a0 = __builtin_amdgcn_mfma_i32_16x16x64_i8(af[ks], wreg[ks][0], a0, 0, 0, 0);
            a1 = __builtin_amdgcn_mfma_i32_16x16x64_i8(af[ks], wreg[ks][1], a1, 0, 0, 0);
        }
        float4 v0, v1;
        v0.x = (float)a0[0]; v0.y = (float)a0[1]; v0.z = (float)a0[2]; v0.w = (float)a0[3];
        v1.x = (float)a1[0]; v1.y = (float)a1[1]; v1.z = (float)a1[2]; v1.w = (float)a1[3];
        *(float4*)(obase + wt * 16)            = v0;   // cout = Q*32 + l15
        *(float4*)(obase + 16 * HW + wt * 16)  = v1;   // cout = Q*32 + 16 + l15
    }
}

extern "C" void kernel_launch(void* const* d_in, const int* in_sizes, int n_in,
                              void* d_out, int out_size, void* d_ws, size_t ws_size,
                              hipStream_t stream) {
    const float* x = (const float*)d_in[0];
    const float* w = (const float*)d_in[1];
    float* out = (float*)d_out;

    char* xq = (char*)d_ws;
    char* wq = xq + XQ_BYTES;

    hipLaunchKernelGGL(k_prep, dim3(NWBLK + NXBLK), dim3(256), 0, stream, x, w, xq, wq);
    hipLaunchKernelGGL(k_conv, dim3(NCONV), dim3(256), 0, stream, xq, wq, out);
}